// Round 1
// baseline (2312.068 us; speedup 1.0000x reference)
//
#include <hip/hip_runtime.h>
#include <math.h>

// WindowAttention fused kernel (fp32 baseline).
// One block per window: B=8192 blocks x 512 threads.
// LDS plan (floats): q 6272 | k 7056 | v 7056 | attn 10192 | u(x->o) 6468 | inv 196
// total ~149 KB < 160 KB/CU -> 1 block/CU, 8 waves.

namespace {
constexpr int N  = 49;    // tokens per window
constexpr int C  = 128;   // channels
constexpr int H  = 4;     // heads
constexpr int HD = 32;    // head dim
constexpr int KS = 36;    // k/v row stride (pad: 36%32=4, 16B aligned)
constexpr int AS = 52;    // attn row stride (pad, 16B aligned)
constexpr int OS = 132;   // o_s row stride (pad, 16B aligned)
constexpr int NT = 512;   // threads per block
constexpr float SCALE = 0.17677669529663687f;  // 32^-0.5
}

__global__ __launch_bounds__(NT, 1) void win_attn(
    const float* __restrict__ x,         // [B,49,128]
    const float* __restrict__ qkv_w,     // [384,128]
    const float* __restrict__ proj_w,    // [128,128]
    const float* __restrict__ proj_b,    // [128]
    const float* __restrict__ table,     // [169,4]
    const float* __restrict__ mask,      // [nW,49,49]
    const int*   __restrict__ pos_index, // [49,49]
    float* __restrict__ out,             // [B,49,128]
    int nW)
{
    __shared__ __align__(16) float q_s[H * N * HD];
    __shared__ __align__(16) float k_s[H * N * KS];
    __shared__ __align__(16) float v_s[H * N * KS];
    __shared__ __align__(16) float attn_s[H * N * AS];
    __shared__ __align__(16) float u_s[N * OS];   // phase1-2: x [n*128+c]; phase5-6: o [n*132+c]
    __shared__ float inv_s[H * N];

    const int tid = threadIdx.x;
    const int blk = blockIdx.x;

    // ---- Phase 1: load x[blk] into LDS (layout [n][c], stride 128) ----
    {
        const float4* xb = (const float4*)(x + (size_t)blk * (N * C));
        float4* xs = (float4*)u_s;
        for (int i = tid; i < N * C / 4; i += NT) xs[i] = xb[i];
    }
    __syncthreads();

    // ---- Phase 2: qkv = x @ qkv_w^T. One thread per output column o (384 cols). ----
    if (tid < 3 * C) {
        const int o = tid;
        float acc[N];
        #pragma unroll
        for (int n = 0; n < N; ++n) acc[n] = 0.f;
        const float4* w4 = (const float4*)(qkv_w + o * C);
        for (int c4 = 0; c4 < C / 4; ++c4) {
            const float4 w = w4[c4];
            #pragma unroll
            for (int n = 0; n < N; ++n) {
                const float4 xv = *(const float4*)(u_s + n * C + c4 * 4);
                acc[n] = fmaf(xv.x, w.x, acc[n]);
                acc[n] = fmaf(xv.y, w.y, acc[n]);
                acc[n] = fmaf(xv.z, w.z, acc[n]);
                acc[n] = fmaf(xv.w, w.w, acc[n]);
            }
        }
        const int s = o >> 7;          // 0=q, 1=k, 2=v
        const int h = (o >> 5) & 3;
        const int d = o & 31;
        if (s == 0) {
            #pragma unroll
            for (int n = 0; n < N; ++n) q_s[(h * N + n) * HD + d] = acc[n] * SCALE;
        } else if (s == 1) {
            #pragma unroll
            for (int n = 0; n < N; ++n) k_s[(h * N + n) * KS + d] = acc[n];
        } else {
            #pragma unroll
            for (int n = 0; n < N; ++n) v_s[(h * N + n) * KS + d] = acc[n];
        }
    }
    __syncthreads();

    // ---- Phase 3: attn[h][n][m] = q.k + pos_bias + mask ----
    {
        const float* mrow = mask + (size_t)(blk % nW) * (N * N);
        for (int e = tid; e < H * N * N; e += NT) {
            const int h = e / (N * N);
            const int r = e - h * (N * N);   // r = n*49 + m
            const int n = r / N;
            const int m = r - n * N;
            const float4* qp = (const float4*)(q_s + (h * N + n) * HD);
            const float4* kp = (const float4*)(k_s + (h * N + m) * KS);
            float acc = 0.f;
            #pragma unroll
            for (int j = 0; j < HD / 4; ++j) {
                const float4 a = qp[j];
                const float4 bb = kp[j];
                acc = fmaf(a.x, bb.x, acc);
                acc = fmaf(a.y, bb.y, acc);
                acc = fmaf(a.z, bb.z, acc);
                acc = fmaf(a.w, bb.w, acc);
            }
            acc += table[pos_index[r] * H + h];
            acc += mrow[r];
            attn_s[(h * N + n) * AS + m] = acc;
        }
    }
    __syncthreads();

    // ---- Phase 4: softmax rows (196 rows; store exp, defer 1/sum) ----
    if (tid < H * N) {
        float* row = attn_s + tid * AS;
        float mx = row[0];
        #pragma unroll
        for (int m = 1; m < N; ++m) mx = fmaxf(mx, row[m]);
        float sum = 0.f;
        #pragma unroll
        for (int m = 0; m < N; ++m) {
            const float ev = __expf(row[m] - mx);
            row[m] = ev;
            sum += ev;
        }
        inv_s[tid] = 1.f / sum;
    }
    __syncthreads();

    // ---- Phase 5: out[h][n][d4] = (attn @ v) * inv_sum -> u_s [n][h*32+d] ----
    for (int e = tid; e < H * N * (HD / 4); e += NT) {   // 1568 float4 outputs
        const int h = e / (N * (HD / 4));
        const int r = e - h * (N * (HD / 4));
        const int n = r >> 3;
        const int d4 = r & 7;
        const float* arow = attn_s + (h * N + n) * AS;
        float4 acc = {0.f, 0.f, 0.f, 0.f};
        for (int m = 0; m < N; ++m) {
            const float a = arow[m];
            const float4 vv = *(const float4*)(v_s + (h * N + m) * KS + d4 * 4);
            acc.x = fmaf(a, vv.x, acc.x);
            acc.y = fmaf(a, vv.y, acc.y);
            acc.z = fmaf(a, vv.z, acc.z);
            acc.w = fmaf(a, vv.w, acc.w);
        }
        const float is = inv_s[h * N + n];
        acc.x *= is; acc.y *= is; acc.z *= is; acc.w *= is;
        *(float4*)(u_s + n * OS + h * HD + d4 * 4) = acc;
    }
    __syncthreads();

    // ---- Phase 6: final = o @ proj_w^T + proj_b. Thread owns col o, n-range split 4 ways. ----
    {
        const int o = tid & (C - 1);
        const int g = tid >> 7;   // 0..3
        const float4* w4 = (const float4*)(proj_w + o * C);
        float acc[13];
        #pragma unroll
        for (int i = 0; i < 13; ++i) acc[i] = 0.f;
        for (int c4 = 0; c4 < C / 4; ++c4) {
            const float4 w = w4[c4];
            #pragma unroll
            for (int i = 0; i < 13; ++i) {
                const int n = g + 4 * i;
                if (n < N) {
                    const float4 xv = *(const float4*)(u_s + n * OS + c4 * 4);
                    acc[i] = fmaf(xv.x, w.x, acc[i]);
                    acc[i] = fmaf(xv.y, w.y, acc[i]);
                    acc[i] = fmaf(xv.z, w.z, acc[i]);
                    acc[i] = fmaf(xv.w, w.w, acc[i]);
                }
            }
        }
        const float bv = proj_b[o];
        float* orow = out + (size_t)blk * (N * C);
        #pragma unroll
        for (int i = 0; i < 13; ++i) {
            const int n = g + 4 * i;
            if (n < N) orow[n * C + o] = acc[i] + bv;
        }
    }
}

extern "C" void kernel_launch(void* const* d_in, const int* in_sizes, int n_in,
                              void* d_out, int out_size, void* d_ws, size_t ws_size,
                              hipStream_t stream) {
    const float* x       = (const float*)d_in[0];
    const float* qkv_w   = (const float*)d_in[1];
    const float* proj_w  = (const float*)d_in[2];
    const float* proj_b  = (const float*)d_in[3];
    const float* table   = (const float*)d_in[4];
    const float* mask    = (const float*)d_in[5];
    const int*   pos_idx = (const int*)d_in[6];
    float* out = (float*)d_out;

    const int B  = in_sizes[0] / (N * C);       // 8192
    const int nW = in_sizes[5] / (N * N);       // 1024

    win_attn<<<B, NT, 0, stream>>>(x, qkv_w, proj_w, proj_b, table, mask, pos_idx, out, nW);
}